// Round 5
// baseline (327.161 us; speedup 1.0000x reference)
//
#include <hip/hip_runtime.h>
#include <math.h>

#define B_MOL 32
#define A_AT  1024
#define NF    128
#define N_AT  (B_MOL * A_AT)

// workspace layout (float offsets)
#define WS_FRAG1    0         // short[16384]: Wr1 bf16 MFMA-B frags
#define WS_FRAG2    8192      // short[16384]: Wr2 frags
#define WS_PRED     16384     // float[N_AT]
#define WS_SIDX     49152     // int[N_AT] sorted->orig
#define WS_SPOS     81920     // float4[N_AT] sorted positions
#define WS_NUMPART  212992    // float[512] per-block softplus partial
#define WS_PREDPART 213504    // float[512] per-block pred partial
#define WS_ENERPART 214016    // float[512] per-block energy partial
#define WS_CTR      214528    // uint[96]: 3 barrier phases x 32 molecules (memset 0)

typedef short short8 __attribute__((ext_vector_type(8)));
typedef float floatx4 __attribute__((ext_vector_type(4)));

__device__ __forceinline__ float fast_rcp(float x) { return __builtin_amdgcn_rcpf(x); }
__device__ __forceinline__ float fast_rsq(float x) { return __builtin_amdgcn_rsqf(x); }
__device__ __forceinline__ float silu_f(float x) { return x * fast_rcp(1.f + __expf(-x)); }

__device__ __forceinline__ short f2bf(float x) {   // RNE f32 -> bf16
  unsigned u = __float_as_uint(x);
  u += 0x7fffu + ((u >> 16) & 1u);
  return (short)(u >> 16);
}

__device__ __forceinline__ float wave_sum(float v) {
#pragma unroll
  for (int o = 32; o > 0; o >>= 1) v += __shfl_xor(v, o, 64);
  return v;
}

// per-molecule barrier among its 16 blocks; deadlock-free because all 512 blocks
// are co-resident (LDS ~51KB -> 3 blocks/CU; __launch_bounds__(256,2) caps VGPR).
__device__ __forceinline__ void mol_barrier(unsigned* c) {
  __threadfence();
  __syncthreads();
  if (threadIdx.x == 0) {
    unsigned prev = __hip_atomic_fetch_add(c, 1u, __ATOMIC_ACQ_REL, __HIP_MEMORY_SCOPE_AGENT);
    if (prev + 1u < 16u) {
      while (__hip_atomic_load(c, __ATOMIC_ACQUIRE, __HIP_MEMORY_SCOPE_AGENT) < 16u)
        __builtin_amdgcn_s_sleep(2);
    }
  }
  __syncthreads();
}

__global__ __launch_bounds__(256, 2) void fused_kernel(
    const float* __restrict__ e_z, const float* __restrict__ charge,
    const float* __restrict__ xyz, const float* __restrict__ W_lin,
    const float* __restrict__ b_lin, const float* __restrict__ k_plus,
    const float* __restrict__ k_minus, const float* __restrict__ v_plus,
    const float* __restrict__ v_minus, const float* __restrict__ Wr1,
    const float* __restrict__ Wr2, const float* __restrict__ Wout,
    const float* __restrict__ w_e, const float* __restrict__ qz_table,
    const int* __restrict__ z, float* __restrict__ ws, float* __restrict__ out) {
  int bx = blockIdx.x, tid = threadIdx.x;
  int mol = bx >> 4, s = bx & 15;
  int base = bx * 64;                       // = mol*1024 + s*64

  __shared__ __align__(16) char big[50176]; // overlay: A: k2/wesh/hist; B: wf+a2s; C: posq
  __shared__ float num_sh[64], ezwe_sh[64], wout_sh[128], awsh[64], vsh[128];
  __shared__ float cc_sh, bsum_sh;

  float* k2 = (float*)big;                  // [128]
  float* wesh = k2 + 128;                   // [128]
  int* hist = (int*)(wesh + 128);           // [64]
  int* startc = hist + 64;                  // [64]
  float* numred = (float*)(startc + 64);    // [4]
  unsigned* ctr = (unsigned*)(ws + WS_CTR);

  float ch = charge[mol];
  bool cpos = ch >= 0.f;
  const float* kvec = cpos ? k_plus : k_minus;

  // ============ Section A ============
  // A1: k2 = W_lin @ kvec (threads 0-127) ; wout_we = Wout @ w_e (threads 128-255)
  {
    int r = tid & 127;
    const float* M = (tid < 128) ? W_lin : Wout;
    const float* vv = (tid < 128) ? kvec : w_e;
    const float4* row = (const float4*)(M + (size_t)r * NF);
    float acc = 0.f;
#pragma unroll 8
    for (int i = 0; i < 32; i++) {
      float4 a = row[i];
      float4 b = ((const float4*)vv)[i];
      acc = fmaf(a.x, b.x, acc); acc = fmaf(a.y, b.y, acc);
      acc = fmaf(a.z, b.z, acc); acc = fmaf(a.w, b.w, acc);
    }
    if (tid < 128) { k2[r] = acc; wesh[r] = w_e[r]; }
    else wout_sh[r] = acc;
  }
  if (tid < 64) {
    float c = b_lin[tid] * kvec[tid] + b_lin[tid + 64] * kvec[tid + 64];
    c = wave_sum(c);
    if (tid == 0) cc_sh = c;
  }
  __syncthreads();

  // A2: attn for own 64 atoms (num/ezwe stay in LDS)
  int w = tid >> 6, l = tid & 63, half = l >> 5, l31 = l & 31;
  {
    int b4 = l31 * 4;
    float ka = k2[b4], kb = k2[b4 + 1], kc = k2[b4 + 2], kd = k2[b4 + 3];
    float wa = wesh[b4], wb = wesh[b4 + 1], wc = wesh[b4 + 2], wd = wesh[b4 + 3];
    float cc = cc_sh;
    float wavenum = 0.f;
#pragma unroll
    for (int it = 0; it < 8; it++) {
      int m = it * 8 + w * 2 + half;
      int n = base + m;
      float4 v = *((const float4*)(e_z + (size_t)n * NF) + l31);  // coalesced
      float dk = v.x * ka; dk = fmaf(v.y, kb, dk); dk = fmaf(v.z, kc, dk); dk = fmaf(v.w, kd, dk);
      float dw = v.x * wa; dw = fmaf(v.y, wb, dw); dw = fmaf(v.z, wc, dw); dw = fmaf(v.w, wd, dw);
#pragma unroll
      for (int o = 1; o < 32; o <<= 1) {
        dk += __shfl_xor(dk, o, 64);
        dw += __shfl_xor(dw, o, 64);
      }
      if (l31 == 0) {
        float arg = (dk + cc) * 0.08838834764831845f;   // 1/sqrt(128)
        float num = fmaxf(arg, 0.f) + log1pf(__expf(-fabsf(arg)));
        num_sh[m] = num;
        ezwe_sh[m] = dw;
        wavenum += num;
      }
    }
    wavenum += __shfl_xor(wavenum, 32, 64);
    if (l == 0) numred[w] = wavenum;
  }
  __syncthreads();
  if (tid == 0) ws[WS_NUMPART + bx] = numred[0] + numred[1] + numred[2] + numred[3];

  // A3 (s==0): spatial counting sort, 4x4x4 cells of 5.5 A
  if (s == 0) {
    if (tid < 64) hist[tid] = 0;
    __syncthreads();
    float px[4], py[4], pz[4];
    int cell[4];
#pragma unroll
    for (int r = 0; r < 4; r++) {
      int j = tid + r * 256;
      const float* p = xyz + (size_t)(mol * A_AT + j) * 3;
      px[r] = p[0]; py[r] = p[1]; pz[r] = p[2];
      int cx = min(3, max(0, (int)(px[r] * (4.f / 22.f))));
      int cy = min(3, max(0, (int)(py[r] * (4.f / 22.f))));
      int cz = min(3, max(0, (int)(pz[r] * (4.f / 22.f))));
      cell[r] = cx * 16 + cy * 4 + cz;
      atomicAdd(&hist[cell[r]], 1);
    }
    __syncthreads();
    if (tid == 0) {
      int acc = 0;
      for (int c = 0; c < 64; c++) { startc[c] = acc; acc += hist[c]; }
    }
    __syncthreads();
    float4* spos = (float4*)(ws + WS_SPOS);
    int* sidx = (int*)(ws + WS_SIDX);
#pragma unroll
    for (int r = 0; r < 4; r++) {
      int j = tid + r * 256;
      int off = atomicAdd(&startc[cell[r]], 1);
      int g = mol * A_AT + off;
      spos[g] = make_float4(px[r], py[r], pz[r], 0.f);
      sidx[g] = j;
    }
  }

  // A4 (s==1): swizzle Wr1/Wr2 into bf16 MFMA-B frag order in ws (32 writers race
  // benignly: identical values). Frag fi=nt*4+ks, lane q*16+n15 holds
  // B[k=ks*32+q*8+j][n=nt*16+n15], j=0..7.
  if (s == 1) {
#pragma unroll
    for (int mtx = 0; mtx < 2; mtx++) {
      const float* W = mtx ? Wr2 : Wr1;
      short* dst = (short*)(ws + (mtx ? WS_FRAG2 : WS_FRAG1));
#pragma unroll
      for (int p = 0; p < 8; p++) {
        int idx = p * 256 + tid;           // 2048 (frag,lane) pairs
        int fi = idx >> 6, ln = idx & 63;
        int nt = fi >> 2, ks = fi & 3;
        int qq = ln >> 4, n15 = ln & 15;
        int k0r = ks * 32 + qq * 8;
        int col = nt * 16 + n15;
        short8 v;
#pragma unroll
        for (int j = 0; j < 8; j++) v[j] = f2bf(W[(size_t)(k0r + j) * NF + col]);
        *(short8*)(dst + (size_t)idx * 8) = v;   // coalesced 16B stores
      }
    }
  }

  mol_barrier(&ctr[mol]);

  // ============ Section B: res_mlp (bf16 MFMA 16x16x32) ============
  if (tid == 0) {
    float t = 0.f;
#pragma unroll
    for (int i = 0; i < 16; i++) t += ws[WS_NUMPART + mol * 16 + i];
    bsum_sh = t;
  }
  if (tid < 128) vsh[tid] = cpos ? v_plus[tid] : v_minus[tid];
  __syncthreads();
  if (tid < 64) awsh[tid] = ch * num_sh[tid] / bsum_sh;

  short* wf = (short*)big;                  // 32 KB
  short* a2s = (short*)(big + 32768);       // 17408 B, [m][k] padded 136
  {
    const float4* src = (const float4*)(ws + WS_FRAG1);
    float4* dst = (float4*)wf;
#pragma unroll
    for (int r = 0; r < 8; r++) dst[tid + r * 256] = src[tid + r * 256];
  }
  __syncthreads();

  int q = l >> 4, l15 = l & 15;
  float aw_m = awsh[w * 16 + l15];
  floatx4 acc1[8];
#pragma unroll
  for (int nt = 0; nt < 8; nt++) acc1[nt] = (floatx4)(0.f);

  // GEMM1: h1 = silu(aw*v) @ Wr1 ; A built in registers
#pragma unroll
  for (int ks = 0; ks < 4; ks++) {
    float4 va = *(const float4*)&vsh[ks * 32 + q * 8];
    float4 vb = *(const float4*)&vsh[ks * 32 + q * 8 + 4];
    short8 af;
    af[0] = f2bf(silu_f(aw_m * va.x)); af[1] = f2bf(silu_f(aw_m * va.y));
    af[2] = f2bf(silu_f(aw_m * va.z)); af[3] = f2bf(silu_f(aw_m * va.w));
    af[4] = f2bf(silu_f(aw_m * vb.x)); af[5] = f2bf(silu_f(aw_m * vb.y));
    af[6] = f2bf(silu_f(aw_m * vb.z)); af[7] = f2bf(silu_f(aw_m * vb.w));
#pragma unroll
    for (int nt = 0; nt < 8; nt++) {
      short8 bf = *(const short8*)&wf[(nt * 4 + ks) * 512 + l * 8 + w * 0];
      acc1[nt] = __builtin_amdgcn_mfma_f32_16x16x32_bf16(af, bf, acc1[nt], 0, 0, 0);
    }
  }

  // silu(h1) -> LDS bf16 [m][k]; C/D layout: row=q*4+r, col=l15
#pragma unroll
  for (int nt = 0; nt < 8; nt++) {
    int f = nt * 16 + l15;
#pragma unroll
    for (int r = 0; r < 4; r++)
      a2s[w * 2176 + (q * 4 + r) * 136 + f] = f2bf(silu_f(acc1[nt][r]));
  }
  __syncthreads();
  {
    const float4* src = (const float4*)(ws + WS_FRAG2);
    float4* dst = (float4*)wf;
#pragma unroll
    for (int r = 0; r < 8; r++) dst[tid + r * 256] = src[tid + r * 256];
  }
  __syncthreads();

  floatx4 acc2[8];
#pragma unroll
  for (int nt = 0; nt < 8; nt++) acc2[nt] = (floatx4)(0.f);

  // GEMM2: h2 = silu(h1) @ Wr2
#pragma unroll
  for (int ks = 0; ks < 4; ks++) {
    short8 af = *(const short8*)&a2s[w * 2176 + l15 * 136 + ks * 32 + q * 8];
#pragma unroll
    for (int nt = 0; nt < 8; nt++) {
      short8 bf = *(const short8*)&wf[(nt * 4 + ks) * 512 + l * 8];
      acc2[nt] = __builtin_amdgcn_mfma_f32_16x16x32_bf16(af, bf, acc2[nt], 0, 0, 0);
    }
  }

  // epilogue: pred = silu(x + h2) . wout_we + e_z.w_e + q_z_table[z]
  float awq[4], part[4];
#pragma unroll
  for (int r = 0; r < 4; r++) {
    awq[r] = awsh[w * 16 + q * 4 + r];
    part[r] = 0.f;
  }
#pragma unroll
  for (int nt = 0; nt < 8; nt++) {
    int f = nt * 16 + l15;
    float vv = vsh[f], ww2 = wout_sh[f];
#pragma unroll
    for (int r = 0; r < 4; r++) {
      float sfl = silu_f(fmaf(awq[r], vv, acc2[nt][r]));
      part[r] = fmaf(sfl, ww2, part[r]);
    }
  }
#pragma unroll
  for (int r = 0; r < 4; r++) {
#pragma unroll
    for (int o = 1; o < 16; o <<= 1) part[r] += __shfl_xor(part[r], o, 64);
  }
  float* pred_shf = (float*)(big + 32768);  // overlay a2s (done with it)
  __syncthreads();
  if (l15 == 0) {
#pragma unroll
    for (int r = 0; r < 4; r++) {
      int m = w * 16 + q * 4 + r;
      int n = base + m;
      float pred = part[r] + ezwe_sh[m] + qz_table[z[n]];
      ws[WS_PRED + n] = pred;
      pred_shf[m] = pred;
    }
  }
  __syncthreads();
  if (tid < 64) {
    float ssum = wave_sum(pred_shf[tid]);
    if (tid == 0) ws[WS_PREDPART + bx] = ssum;
  }

  mol_barrier(&ctr[32 + mol]);

  // ============ Section C: triangle-decomposed switched Coulomb ============
  if (tid == 0) {
    float t = 0.f;
#pragma unroll
    for (int i = 0; i < 16; i++) t += ws[WS_PREDPART + mol * 16 + i];
    bsum_sh = t;
  }
  __syncthreads();
  float corr = (ch - bsum_sh) * (1.f / 1024.f);
  float4* posq = (float4*)big;              // overlay, 16 KB
  const float4* spos = (const float4*)(ws + WS_SPOS);
  const int* sidx = (const int*)(ws + WS_SIDX);
  for (int j = tid; j < 1024; j += 256) {
    float4 p = spos[mol * 1024 + j];
    p.w = ws[WS_PRED + mol * 1024 + sidx[mol * 1024 + j]] + corr;
    posq[j] = p;
  }
  __syncthreads();
  int i = s * 64 + l;
  float4 me = posq[i];
  float e = 0.f;
  for (int c = s + w; c < 16; c += 4) {
    int j0 = c * 64;
    if (c == s) {                           // diagonal chunk: mask j <= i
#pragma unroll 4
      for (int j = j0; j < j0 + 64; j++) {
        float4 p = posq[j];
        float dx = me.x - p.x, dy = me.y - p.y, dz = me.z - p.z;
        float r2 = fmaf(dx, dx, fmaf(dy, dy, dz * dz));
        bool skip = (j <= i);
        float r2s = skip ? 1.0e8f : r2;
        float qj = skip ? 0.f : p.w;
        float inv_r = fast_rsq(r2s);
        e = fmaf(qj, inv_r, e);
        if (__any(r2s < 14.0625f)) {        // R_OFF^2
          float r = r2s * inv_r;
          float arg = (r - 1.25f) * 0.4f;
          float argc = fminf(fmaxf(arg, 1e-6f), 1.f - 1e-6f);
          float t = fast_rcp(argc) - fast_rcp(1.f - argc);
          float fs = fast_rcp(1.f + __expf(-t));
          float delta = fs * (fast_rsq(r2s + 1.f) - inv_r);
          e = fmaf(qj, delta, e);
        }
      }
    } else {
#pragma unroll 4
      for (int j = j0; j < j0 + 64; j++) {
        float4 p = posq[j];
        float dx = me.x - p.x, dy = me.y - p.y, dz = me.z - p.z;
        float r2 = fmaf(dx, dx, fmaf(dy, dy, dz * dz));
        float qj = p.w;
        float inv_r = fast_rsq(r2);
        e = fmaf(qj, inv_r, e);
        if (__any(r2 < 14.0625f)) {
          float r = r2 * inv_r;
          float arg = (r - 1.25f) * 0.4f;
          float argc = fminf(fmaxf(arg, 1e-6f), 1.f - 1e-6f);
          float t = fast_rcp(argc) - fast_rcp(1.f - argc);
          float fs = fast_rcp(1.f + __expf(-t));
          float delta = fs * (fast_rsq(r2 + 1.f) - inv_r);
          e = fmaf(qj, delta, e);
        }
      }
    }
  }
  e *= me.w;
  float sred = wave_sum(e);
  if (l == 0) awsh[w] = sred;               // reuse awsh as 4-float scratch
  __syncthreads();
  if (tid == 0) {
    ws[WS_ENERPART + bx] = 332.0636f * (awsh[0] + awsh[1] + awsh[2] + awsh[3]);
    __threadfence();
    unsigned prev = __hip_atomic_fetch_add(&ctr[64 + mol], 1u,
                                           __ATOMIC_ACQ_REL, __HIP_MEMORY_SCOPE_AGENT);
    if (prev == 15u) {                      // last arriver writes the energy
      float tot = 0.f;
#pragma unroll
      for (int i2 = 0; i2 < 16; i2++) tot += ws[WS_ENERPART + mol * 16 + i2];
      out[mol] = tot;
    }
  }
}

extern "C" void kernel_launch(void* const* d_in, const int* in_sizes, int n_in,
                              void* d_out, int out_size, void* d_ws, size_t ws_size,
                              hipStream_t stream) {
  const float* e_z     = (const float*)d_in[0];
  const float* charge  = (const float*)d_in[1];
  const float* xyz     = (const float*)d_in[2];
  const float* W_lin   = (const float*)d_in[3];
  const float* b_lin   = (const float*)d_in[4];
  const float* k_plus  = (const float*)d_in[5];
  const float* k_minus = (const float*)d_in[6];
  const float* v_plus  = (const float*)d_in[7];
  const float* v_minus = (const float*)d_in[8];
  const float* Wr1     = (const float*)d_in[9];
  const float* Wr2     = (const float*)d_in[10];
  const float* Wout    = (const float*)d_in[11];
  const float* w_e     = (const float*)d_in[12];
  const float* qz      = (const float*)d_in[13];
  const int*   z       = (const int*)d_in[14];
  float* out = (float*)d_out;
  float* ws  = (float*)d_ws;

  hipMemsetAsync(ws + WS_CTR, 0, 96 * sizeof(unsigned), stream);
  fused_kernel<<<512, 256, 0, stream>>>(e_z, charge, xyz, W_lin, b_lin,
                                        k_plus, k_minus, v_plus, v_minus,
                                        Wr1, Wr2, Wout, w_e, qz, z, ws, out);
}

// Round 6
// 240.294 us; speedup vs baseline: 1.3615x; 1.3615x over previous
//
#include <hip/hip_runtime.h>
#include <math.h>

#define B_MOL 32
#define A_AT  1024
#define NF    128
#define N_AT  (B_MOL * A_AT)

// workspace layout (float offsets)
#define WS_FRAG1    0         // short[16384]: Wr1 bf16 MFMA-B frags
#define WS_FRAG2    8192      // short[16384]: Wr2 frags
#define WS_PRED     16384     // float[N_AT]
#define WS_SIDX     49152     // int[N_AT] sorted->orig
#define WS_SPOS     81920     // float4[N_AT] sorted positions
#define WS_NUMPART  212992    // float[512] per-block softplus partial
#define WS_PREDPART 213504    // float[512] per-block pred partial
#define WS_ENERPART 214016    // float[512] per-block energy partial
#define WS_CTR      214528    // uint[96]: 3 barrier phases x 32 molecules (memset 0)

typedef short short8 __attribute__((ext_vector_type(8)));
typedef float floatx4 __attribute__((ext_vector_type(4)));

__device__ __forceinline__ float fast_rcp(float x) { return __builtin_amdgcn_rcpf(x); }
__device__ __forceinline__ float fast_rsq(float x) { return __builtin_amdgcn_rsqf(x); }
__device__ __forceinline__ float silu_f(float x) { return x * fast_rcp(1.f + __expf(-x)); }

__device__ __forceinline__ short f2bf(float x) {   // RNE f32 -> bf16
  unsigned u = __float_as_uint(x);
  u += 0x7fffu + ((u >> 16) & 1u);
  return (short)(u >> 16);
}

__device__ __forceinline__ float wave_sum(float v) {
#pragma unroll
  for (int o = 32; o > 0; o >>= 1) v += __shfl_xor(v, o, 64);
  return v;
}

// Per-molecule barrier among its 16 blocks. Deadlock-free: all 512 blocks
// co-resident (51 KB LDS -> 3 blocks/CU cap, need 2). Cache-maintenance
// minimized: ONE threadfence (wb) + relaxed add + RELAXED polls (no inv per
// poll!) + ONE threadfence (inv) — all by thread 0 only. R5's version did
// 256 fences/block + acquire-per-poll L2 invalidate storms -> 250 us idle.
__device__ __forceinline__ void mol_barrier(unsigned* c) {
  __syncthreads();                  // all waves drain vmcnt -> writes in L2
  if (threadIdx.x == 0) {
    __threadfence();                // writeback: block's writes -> coherence point
    __hip_atomic_fetch_add(c, 1u, __ATOMIC_RELAXED, __HIP_MEMORY_SCOPE_AGENT);
    while (__hip_atomic_load(c, __ATOMIC_RELAXED, __HIP_MEMORY_SCOPE_AGENT) < 16u)
      __builtin_amdgcn_s_sleep(8);
    __threadfence();                // invalidate: fresh view of peers' writes
  }
  __syncthreads();
}

__global__ __launch_bounds__(256, 2) void fused_kernel(
    const float* __restrict__ e_z, const float* __restrict__ charge,
    const float* __restrict__ xyz, const float* __restrict__ W_lin,
    const float* __restrict__ b_lin, const float* __restrict__ k_plus,
    const float* __restrict__ k_minus, const float* __restrict__ v_plus,
    const float* __restrict__ v_minus, const float* __restrict__ Wr1,
    const float* __restrict__ Wr2, const float* __restrict__ Wout,
    const float* __restrict__ w_e, const float* __restrict__ qz_table,
    const int* __restrict__ z, float* __restrict__ ws, float* __restrict__ out) {
  int bx = blockIdx.x, tid = threadIdx.x;
  int mol = bx >> 4, s = bx & 15;
  int base = bx * 64;                       // = mol*1024 + s*64

  __shared__ __align__(16) char big[50176]; // overlay: A: k2/wesh/hist; B: wf+a2s; C: posq
  __shared__ float num_sh[64], ezwe_sh[64], wout_sh[128], awsh[64], vsh[128];
  __shared__ float cc_sh, bsum_sh;

  float* k2 = (float*)big;                  // [128]
  float* wesh = k2 + 128;                   // [128]
  int* hist = (int*)(wesh + 128);           // [64]
  int* startc = hist + 64;                  // [64]
  float* numred = (float*)(startc + 64);    // [4]
  unsigned* ctr = (unsigned*)(ws + WS_CTR);

  float ch = charge[mol];
  bool cpos = ch >= 0.f;
  const float* kvec = cpos ? k_plus : k_minus;

  // ============ Section A ============
  // A1: k2 = W_lin @ kvec (threads 0-127) ; wout_we = Wout @ w_e (threads 128-255)
  {
    int r = tid & 127;
    const float* M = (tid < 128) ? W_lin : Wout;
    const float* vv = (tid < 128) ? kvec : w_e;
    const float4* row = (const float4*)(M + (size_t)r * NF);
    float acc = 0.f;
#pragma unroll 8
    for (int i = 0; i < 32; i++) {
      float4 a = row[i];
      float4 b = ((const float4*)vv)[i];
      acc = fmaf(a.x, b.x, acc); acc = fmaf(a.y, b.y, acc);
      acc = fmaf(a.z, b.z, acc); acc = fmaf(a.w, b.w, acc);
    }
    if (tid < 128) { k2[r] = acc; wesh[r] = w_e[r]; }
    else wout_sh[r] = acc;
  }
  if (tid < 64) {
    float c = b_lin[tid] * kvec[tid] + b_lin[tid + 64] * kvec[tid + 64];
    c = wave_sum(c);
    if (tid == 0) cc_sh = c;
  }
  __syncthreads();

  // A2: attn for own 64 atoms (num/ezwe stay in LDS)
  int w = tid >> 6, l = tid & 63, half = l >> 5, l31 = l & 31;
  {
    int b4 = l31 * 4;
    float ka = k2[b4], kb = k2[b4 + 1], kc = k2[b4 + 2], kd = k2[b4 + 3];
    float wa = wesh[b4], wb = wesh[b4 + 1], wc = wesh[b4 + 2], wd = wesh[b4 + 3];
    float cc = cc_sh;
    float wavenum = 0.f;
#pragma unroll
    for (int it = 0; it < 8; it++) {
      int m = it * 8 + w * 2 + half;
      int n = base + m;
      float4 v = *((const float4*)(e_z + (size_t)n * NF) + l31);  // coalesced
      float dk = v.x * ka; dk = fmaf(v.y, kb, dk); dk = fmaf(v.z, kc, dk); dk = fmaf(v.w, kd, dk);
      float dw = v.x * wa; dw = fmaf(v.y, wb, dw); dw = fmaf(v.z, wc, dw); dw = fmaf(v.w, wd, dw);
#pragma unroll
      for (int o = 1; o < 32; o <<= 1) {
        dk += __shfl_xor(dk, o, 64);
        dw += __shfl_xor(dw, o, 64);
      }
      if (l31 == 0) {
        float arg = (dk + cc) * 0.08838834764831845f;   // 1/sqrt(128)
        float num = fmaxf(arg, 0.f) + log1pf(__expf(-fabsf(arg)));
        num_sh[m] = num;
        ezwe_sh[m] = dw;
        wavenum += num;
      }
    }
    wavenum += __shfl_xor(wavenum, 32, 64);
    if (l == 0) numred[w] = wavenum;
  }
  __syncthreads();
  if (tid == 0) ws[WS_NUMPART + bx] = numred[0] + numred[1] + numred[2] + numred[3];

  // A3 (s==0): spatial counting sort, 4x4x4 cells of 5.5 A
  if (s == 0) {
    if (tid < 64) hist[tid] = 0;
    __syncthreads();
    float px[4], py[4], pz[4];
    int cell[4];
#pragma unroll
    for (int r = 0; r < 4; r++) {
      int j = tid + r * 256;
      const float* p = xyz + (size_t)(mol * A_AT + j) * 3;
      px[r] = p[0]; py[r] = p[1]; pz[r] = p[2];
      int cx = min(3, max(0, (int)(px[r] * (4.f / 22.f))));
      int cy = min(3, max(0, (int)(py[r] * (4.f / 22.f))));
      int cz = min(3, max(0, (int)(pz[r] * (4.f / 22.f))));
      cell[r] = cx * 16 + cy * 4 + cz;
      atomicAdd(&hist[cell[r]], 1);
    }
    __syncthreads();
    if (tid == 0) {
      int acc = 0;
      for (int c = 0; c < 64; c++) { startc[c] = acc; acc += hist[c]; }
    }
    __syncthreads();
    float4* spos = (float4*)(ws + WS_SPOS);
    int* sidx = (int*)(ws + WS_SIDX);
#pragma unroll
    for (int r = 0; r < 4; r++) {
      int j = tid + r * 256;
      int off = atomicAdd(&startc[cell[r]], 1);
      int g = mol * A_AT + off;
      spos[g] = make_float4(px[r], py[r], pz[r], 0.f);
      sidx[g] = j;
    }
  }

  // A4: weight swizzle distributed across the molecule's 16 blocks (1/16 each;
  // matrix = s&1, share = s>>1; 32 molecules write identical values — benign).
  // Frag fi=nt*4+ks, lane q*16+n15 holds B[k=ks*32+q*8+j][n=nt*16+n15], j=0..7.
  {
    const float* W = (s & 1) ? Wr2 : Wr1;
    short* dst = (short*)(ws + ((s & 1) ? WS_FRAG2 : WS_FRAG1));
    int idx = (s >> 1) * 256 + tid;        // 2048 (frag,lane) pairs per matrix
    int fi = idx >> 6, ln = idx & 63;
    int nt = fi >> 2, ks = fi & 3;
    int qq = ln >> 4, n15 = ln & 15;
    int k0r = ks * 32 + qq * 8;
    int col = nt * 16 + n15;
    short8 v;
#pragma unroll
    for (int j = 0; j < 8; j++) v[j] = f2bf(W[(size_t)(k0r + j) * NF + col]);
    *(short8*)(dst + (size_t)idx * 8) = v; // coalesced 16B stores
  }

  mol_barrier(&ctr[mol]);

  // ============ Section B: res_mlp (bf16 MFMA 16x16x32) ============
  if (tid == 0) {
    float t = 0.f;
#pragma unroll
    for (int i = 0; i < 16; i++) t += ws[WS_NUMPART + mol * 16 + i];
    bsum_sh = t;
  }
  if (tid < 128) vsh[tid] = cpos ? v_plus[tid] : v_minus[tid];
  __syncthreads();
  if (tid < 64) awsh[tid] = ch * num_sh[tid] / bsum_sh;

  short* wf = (short*)big;                  // 32 KB
  short* a2s = (short*)(big + 32768);       // 17408 B, [m][k] padded 136
  {
    const float4* src = (const float4*)(ws + WS_FRAG1);
    float4* dst = (float4*)wf;
#pragma unroll
    for (int r = 0; r < 8; r++) dst[tid + r * 256] = src[tid + r * 256];
  }
  __syncthreads();

  int q = l >> 4, l15 = l & 15;
  float aw_m = awsh[w * 16 + l15];
  floatx4 acc1[8];
#pragma unroll
  for (int nt = 0; nt < 8; nt++) acc1[nt] = (floatx4)(0.f);

  // GEMM1: h1 = silu(aw*v) @ Wr1 ; A built in registers
#pragma unroll
  for (int ks = 0; ks < 4; ks++) {
    float4 va = *(const float4*)&vsh[ks * 32 + q * 8];
    float4 vb = *(const float4*)&vsh[ks * 32 + q * 8 + 4];
    short8 af;
    af[0] = f2bf(silu_f(aw_m * va.x)); af[1] = f2bf(silu_f(aw_m * va.y));
    af[2] = f2bf(silu_f(aw_m * va.z)); af[3] = f2bf(silu_f(aw_m * va.w));
    af[4] = f2bf(silu_f(aw_m * vb.x)); af[5] = f2bf(silu_f(aw_m * vb.y));
    af[6] = f2bf(silu_f(aw_m * vb.z)); af[7] = f2bf(silu_f(aw_m * vb.w));
#pragma unroll
    for (int nt = 0; nt < 8; nt++) {
      short8 bf = *(const short8*)&wf[(nt * 4 + ks) * 512 + l * 8];
      acc1[nt] = __builtin_amdgcn_mfma_f32_16x16x32_bf16(af, bf, acc1[nt], 0, 0, 0);
    }
  }

  // silu(h1) -> LDS bf16 [m][k]; C/D layout: row=q*4+r, col=l15
#pragma unroll
  for (int nt = 0; nt < 8; nt++) {
    int f = nt * 16 + l15;
#pragma unroll
    for (int r = 0; r < 4; r++)
      a2s[w * 2176 + (q * 4 + r) * 136 + f] = f2bf(silu_f(acc1[nt][r]));
  }
  __syncthreads();
  {
    const float4* src = (const float4*)(ws + WS_FRAG2);
    float4* dst = (float4*)wf;
#pragma unroll
    for (int r = 0; r < 8; r++) dst[tid + r * 256] = src[tid + r * 256];
  }
  __syncthreads();

  floatx4 acc2[8];
#pragma unroll
  for (int nt = 0; nt < 8; nt++) acc2[nt] = (floatx4)(0.f);

  // GEMM2: h2 = silu(h1) @ Wr2
#pragma unroll
  for (int ks = 0; ks < 4; ks++) {
    short8 af = *(const short8*)&a2s[w * 2176 + l15 * 136 + ks * 32 + q * 8];
#pragma unroll
    for (int nt = 0; nt < 8; nt++) {
      short8 bf = *(const short8*)&wf[(nt * 4 + ks) * 512 + l * 8];
      acc2[nt] = __builtin_amdgcn_mfma_f32_16x16x32_bf16(af, bf, acc2[nt], 0, 0, 0);
    }
  }

  // epilogue: pred = silu(x + h2) . wout_we + e_z.w_e + q_z_table[z]
  float awq[4], part[4];
#pragma unroll
  for (int r = 0; r < 4; r++) {
    awq[r] = awsh[w * 16 + q * 4 + r];
    part[r] = 0.f;
  }
#pragma unroll
  for (int nt = 0; nt < 8; nt++) {
    int f = nt * 16 + l15;
    float vv = vsh[f], ww2 = wout_sh[f];
#pragma unroll
    for (int r = 0; r < 4; r++) {
      float sfl = silu_f(fmaf(awq[r], vv, acc2[nt][r]));
      part[r] = fmaf(sfl, ww2, part[r]);
    }
  }
#pragma unroll
  for (int r = 0; r < 4; r++) {
#pragma unroll
    for (int o = 1; o < 16; o <<= 1) part[r] += __shfl_xor(part[r], o, 64);
  }
  float* pred_shf = (float*)(big + 32768);  // overlay a2s (done with it)
  __syncthreads();
  if (l15 == 0) {
#pragma unroll
    for (int r = 0; r < 4; r++) {
      int m = w * 16 + q * 4 + r;
      int n = base + m;
      float pred = part[r] + ezwe_sh[m] + qz_table[z[n]];
      ws[WS_PRED + n] = pred;
      pred_shf[m] = pred;
    }
  }
  __syncthreads();
  if (tid < 64) {
    float ssum = wave_sum(pred_shf[tid]);
    if (tid == 0) ws[WS_PREDPART + bx] = ssum;
  }

  mol_barrier(&ctr[32 + mol]);

  // ============ Section C: triangle-decomposed switched Coulomb ============
  if (tid == 0) {
    float t = 0.f;
#pragma unroll
    for (int i = 0; i < 16; i++) t += ws[WS_PREDPART + mol * 16 + i];
    bsum_sh = t;
  }
  __syncthreads();
  float corr = (ch - bsum_sh) * (1.f / 1024.f);
  float4* posq = (float4*)big;              // overlay, 16 KB
  const float4* spos = (const float4*)(ws + WS_SPOS);
  const int* sidx = (const int*)(ws + WS_SIDX);
  for (int j = tid; j < 1024; j += 256) {
    float4 p = spos[mol * 1024 + j];
    p.w = ws[WS_PRED + mol * 1024 + sidx[mol * 1024 + j]] + corr;
    posq[j] = p;
  }
  __syncthreads();
  int i = s * 64 + l;
  float4 me = posq[i];
  float e = 0.f;
  for (int c = s + w; c < 16; c += 4) {
    int j0 = c * 64;
    if (c == s) {                           // diagonal chunk: mask j <= i
#pragma unroll 4
      for (int j = j0; j < j0 + 64; j++) {
        float4 p = posq[j];
        float dx = me.x - p.x, dy = me.y - p.y, dz = me.z - p.z;
        float r2 = fmaf(dx, dx, fmaf(dy, dy, dz * dz));
        bool skip = (j <= i);
        float r2s = skip ? 1.0e8f : r2;
        float qj = skip ? 0.f : p.w;
        float inv_r = fast_rsq(r2s);
        e = fmaf(qj, inv_r, e);
        if (__any(r2s < 14.0625f)) {        // R_OFF^2
          float r = r2s * inv_r;
          float arg = (r - 1.25f) * 0.4f;
          float argc = fminf(fmaxf(arg, 1e-6f), 1.f - 1e-6f);
          float t = fast_rcp(argc) - fast_rcp(1.f - argc);
          float fs = fast_rcp(1.f + __expf(-t));
          float delta = fs * (fast_rsq(r2s + 1.f) - inv_r);
          e = fmaf(qj, delta, e);
        }
      }
    } else {
#pragma unroll 4
      for (int j = j0; j < j0 + 64; j++) {
        float4 p = posq[j];
        float dx = me.x - p.x, dy = me.y - p.y, dz = me.z - p.z;
        float r2 = fmaf(dx, dx, fmaf(dy, dy, dz * dz));
        float qj = p.w;
        float inv_r = fast_rsq(r2);
        e = fmaf(qj, inv_r, e);
        if (__any(r2 < 14.0625f)) {
          float r = r2 * inv_r;
          float arg = (r - 1.25f) * 0.4f;
          float argc = fminf(fmaxf(arg, 1e-6f), 1.f - 1e-6f);
          float t = fast_rcp(argc) - fast_rcp(1.f - argc);
          float fs = fast_rcp(1.f + __expf(-t));
          float delta = fs * (fast_rsq(r2 + 1.f) - inv_r);
          e = fmaf(qj, delta, e);
        }
      }
    }
  }
  e *= me.w;
  float sred = wave_sum(e);
  if (l == 0) awsh[w] = sred;               // reuse awsh as 4-float scratch
  __syncthreads();
  if (tid == 0) {
    ws[WS_ENERPART + bx] = 332.0636f * (awsh[0] + awsh[1] + awsh[2] + awsh[3]);
    __threadfence();                        // wb own partial
    unsigned prev = __hip_atomic_fetch_add(&ctr[64 + mol], 1u,
                                           __ATOMIC_RELAXED, __HIP_MEMORY_SCOPE_AGENT);
    if (prev == 15u) {                      // last arriver writes the energy
      __threadfence();                      // inv: fresh view of peers' partials
      float tot = 0.f;
#pragma unroll
      for (int i2 = 0; i2 < 16; i2++) tot += ws[WS_ENERPART + mol * 16 + i2];
      out[mol] = tot;
    }
  }
}

extern "C" void kernel_launch(void* const* d_in, const int* in_sizes, int n_in,
                              void* d_out, int out_size, void* d_ws, size_t ws_size,
                              hipStream_t stream) {
  const float* e_z     = (const float*)d_in[0];
  const float* charge  = (const float*)d_in[1];
  const float* xyz     = (const float*)d_in[2];
  const float* W_lin   = (const float*)d_in[3];
  const float* b_lin   = (const float*)d_in[4];
  const float* k_plus  = (const float*)d_in[5];
  const float* k_minus = (const float*)d_in[6];
  const float* v_plus  = (const float*)d_in[7];
  const float* v_minus = (const float*)d_in[8];
  const float* Wr1     = (const float*)d_in[9];
  const float* Wr2     = (const float*)d_in[10];
  const float* Wout    = (const float*)d_in[11];
  const float* w_e     = (const float*)d_in[12];
  const float* qz      = (const float*)d_in[13];
  const int*   z       = (const int*)d_in[14];
  float* out = (float*)d_out;
  float* ws  = (float*)d_ws;

  hipMemsetAsync(ws + WS_CTR, 0, 96 * sizeof(unsigned), stream);
  fused_kernel<<<512, 256, 0, stream>>>(e_z, charge, xyz, W_lin, b_lin,
                                        k_plus, k_minus, v_plus, v_minus,
                                        Wr1, Wr2, Wout, w_e, qz, z, ws, out);
}

// Round 7
// 237.704 us; speedup vs baseline: 1.3763x; 1.0109x over previous
//
#include <hip/hip_runtime.h>
#include <math.h>

#define B_MOL 32
#define A_AT  1024
#define NF    128
#define N_AT  (B_MOL * A_AT)

// workspace layout (float offsets)
#define WS_FRAG1    0         // short[16384]: Wr1 bf16 MFMA-B frags
#define WS_FRAG2    8192      // short[16384]: Wr2 frags
#define WS_PRED     16384     // float[N_AT]
#define WS_SIDX     49152     // int[N_AT] sorted->orig
#define WS_SPOS     81920     // float4[N_AT] sorted positions
#define WS_NUMPART  212992    // float[512] per-block softplus partial
#define WS_PREDPART 213504    // float[512] per-block pred partial
#define WS_CTR      214528    // uint[64]: 2 barrier phases x 32 molecules (memset 0)

typedef short short8 __attribute__((ext_vector_type(8)));
typedef float floatx4 __attribute__((ext_vector_type(4)));

__device__ __forceinline__ float fast_rcp(float x) { return __builtin_amdgcn_rcpf(x); }
__device__ __forceinline__ float fast_rsq(float x) { return __builtin_amdgcn_rsqf(x); }
__device__ __forceinline__ float silu_f(float x) { return x * fast_rcp(1.f + __expf(-x)); }

__device__ __forceinline__ short f2bf(float x) {   // RNE f32 -> bf16
  unsigned u = __float_as_uint(x);
  u += 0x7fffu + ((u >> 16) & 1u);
  return (short)(u >> 16);
}

__device__ __forceinline__ float wave_sum(float v) {
#pragma unroll
  for (int o = 32; o > 0; o >>= 1) v += __shfl_xor(v, o, 64);
  return v;
}

// Per-molecule barrier among its 16 blocks. Deadlock-free: all 512 blocks
// co-resident (51 KB LDS -> 3 blocks/CU cap, need 2; VGPR 72).
// KEY gfx950 lesson (R5/R6): poll with an atomic RMW (fetch_add 0), NOT a
// load. Per-XCD L2s are not cross-coherent: an ACQUIRE load invalidates L2
// every poll (R5: 250us storm), a RELAXED load is served from a STALE local
// L2 line until random eviction (R6: ~50us/barrier). RMW executes at the
// device coherence point -> fresh value, ~cheap. One wb-fence before
// arrival, one inv-fence after release, thread 0 only.
__device__ __forceinline__ void mol_barrier(unsigned* c) {
  __syncthreads();                  // all waves' global writes issued
  if (threadIdx.x == 0) {
    __threadfence();                // writeback: block's writes -> coherence point
    __hip_atomic_fetch_add(c, 1u, __ATOMIC_RELAXED, __HIP_MEMORY_SCOPE_AGENT);
    while (__hip_atomic_fetch_add(c, 0u, __ATOMIC_RELAXED,
                                  __HIP_MEMORY_SCOPE_AGENT) < 16u)
      __builtin_amdgcn_s_sleep(2);
    __threadfence();                // invalidate: fresh view of peers' writes
  }
  __syncthreads();
}

__global__ __launch_bounds__(256, 2) void fused_kernel(
    const float* __restrict__ e_z, const float* __restrict__ charge,
    const float* __restrict__ xyz, const float* __restrict__ W_lin,
    const float* __restrict__ b_lin, const float* __restrict__ k_plus,
    const float* __restrict__ k_minus, const float* __restrict__ v_plus,
    const float* __restrict__ v_minus, const float* __restrict__ Wr1,
    const float* __restrict__ Wr2, const float* __restrict__ Wout,
    const float* __restrict__ w_e, const float* __restrict__ qz_table,
    const int* __restrict__ z, float* __restrict__ ws, float* __restrict__ out) {
  int bx = blockIdx.x, tid = threadIdx.x;
  int mol = bx >> 4, s = bx & 15;
  int base = bx * 64;                       // = mol*1024 + s*64

  __shared__ __align__(16) char big[50176]; // overlay: A: k2/wesh/hist; B: wf+a2s; C: posq
  __shared__ float num_sh[64], ezwe_sh[64], wout_sh[128], awsh[64], vsh[128];
  __shared__ float cc_sh, bsum_sh;

  float* k2 = (float*)big;                  // [128]
  float* wesh = k2 + 128;                   // [128]
  int* hist = (int*)(wesh + 128);           // [64]
  int* startc = hist + 64;                  // [64]
  float* numred = (float*)(startc + 64);    // [4]
  unsigned* ctr = (unsigned*)(ws + WS_CTR);

  float ch = charge[mol];
  bool cpos = ch >= 0.f;
  const float* kvec = cpos ? k_plus : k_minus;

  // ============ Section A ============
  // A1: k2 = W_lin @ kvec (threads 0-127) ; wout_we = Wout @ w_e (threads 128-255)
  {
    int r = tid & 127;
    const float* M = (tid < 128) ? W_lin : Wout;
    const float* vv = (tid < 128) ? kvec : w_e;
    const float4* row = (const float4*)(M + (size_t)r * NF);
    float acc = 0.f;
#pragma unroll 8
    for (int i = 0; i < 32; i++) {
      float4 a = row[i];
      float4 b = ((const float4*)vv)[i];
      acc = fmaf(a.x, b.x, acc); acc = fmaf(a.y, b.y, acc);
      acc = fmaf(a.z, b.z, acc); acc = fmaf(a.w, b.w, acc);
    }
    if (tid < 128) { k2[r] = acc; wesh[r] = w_e[r]; }
    else wout_sh[r] = acc;
  }
  if (tid < 64) {
    float c = b_lin[tid] * kvec[tid] + b_lin[tid + 64] * kvec[tid + 64];
    c = wave_sum(c);
    if (tid == 0) cc_sh = c;
  }
  __syncthreads();

  // A2: attn for own 64 atoms (num/ezwe stay in LDS)
  int w = tid >> 6, l = tid & 63, half = l >> 5, l31 = l & 31;
  {
    int b4 = l31 * 4;
    float ka = k2[b4], kb = k2[b4 + 1], kc = k2[b4 + 2], kd = k2[b4 + 3];
    float wa = wesh[b4], wb = wesh[b4 + 1], wc = wesh[b4 + 2], wd = wesh[b4 + 3];
    float cc = cc_sh;
    float wavenum = 0.f;
#pragma unroll
    for (int it = 0; it < 8; it++) {
      int m = it * 8 + w * 2 + half;
      int n = base + m;
      float4 v = *((const float4*)(e_z + (size_t)n * NF) + l31);  // coalesced
      float dk = v.x * ka; dk = fmaf(v.y, kb, dk); dk = fmaf(v.z, kc, dk); dk = fmaf(v.w, kd, dk);
      float dw = v.x * wa; dw = fmaf(v.y, wb, dw); dw = fmaf(v.z, wc, dw); dw = fmaf(v.w, wd, dw);
#pragma unroll
      for (int o = 1; o < 32; o <<= 1) {
        dk += __shfl_xor(dk, o, 64);
        dw += __shfl_xor(dw, o, 64);
      }
      if (l31 == 0) {
        float arg = (dk + cc) * 0.08838834764831845f;   // 1/sqrt(128)
        float num = fmaxf(arg, 0.f) + log1pf(__expf(-fabsf(arg)));
        num_sh[m] = num;
        ezwe_sh[m] = dw;
        wavenum += num;
      }
    }
    wavenum += __shfl_xor(wavenum, 32, 64);
    if (l == 0) numred[w] = wavenum;
  }
  __syncthreads();
  if (tid == 0) ws[WS_NUMPART + bx] = numred[0] + numred[1] + numred[2] + numred[3];

  // A3 (s==0): spatial counting sort, 4x4x4 cells of 5.5 A
  if (s == 0) {
    if (tid < 64) hist[tid] = 0;
    __syncthreads();
    float px[4], py[4], pz[4];
    int cell[4];
#pragma unroll
    for (int r = 0; r < 4; r++) {
      int j = tid + r * 256;
      const float* p = xyz + (size_t)(mol * A_AT + j) * 3;
      px[r] = p[0]; py[r] = p[1]; pz[r] = p[2];
      int cx = min(3, max(0, (int)(px[r] * (4.f / 22.f))));
      int cy = min(3, max(0, (int)(py[r] * (4.f / 22.f))));
      int cz = min(3, max(0, (int)(pz[r] * (4.f / 22.f))));
      cell[r] = cx * 16 + cy * 4 + cz;
      atomicAdd(&hist[cell[r]], 1);
    }
    __syncthreads();
    if (tid == 0) {
      int acc = 0;
      for (int c = 0; c < 64; c++) { startc[c] = acc; acc += hist[c]; }
    }
    __syncthreads();
    float4* spos = (float4*)(ws + WS_SPOS);
    int* sidx = (int*)(ws + WS_SIDX);
#pragma unroll
    for (int r = 0; r < 4; r++) {
      int j = tid + r * 256;
      int off = atomicAdd(&startc[cell[r]], 1);
      int g = mol * A_AT + off;
      spos[g] = make_float4(px[r], py[r], pz[r], 0.f);
      sidx[g] = j;
    }
  }

  // A4: weight swizzle distributed across the molecule's 16 blocks (1/16 each;
  // matrix = s&1, share = s>>1; 32 molecules write identical values — benign).
  // Frag fi=nt*4+ks, lane q*16+n15 holds B[k=ks*32+q*8+j][n=nt*16+n15], j=0..7.
  {
    const float* W = (s & 1) ? Wr2 : Wr1;
    short* dst = (short*)(ws + ((s & 1) ? WS_FRAG2 : WS_FRAG1));
    int idx = (s >> 1) * 256 + tid;        // 2048 (frag,lane) pairs per matrix
    int fi = idx >> 6, ln = idx & 63;
    int nt = fi >> 2, ks = fi & 3;
    int qq = ln >> 4, n15 = ln & 15;
    int k0r = ks * 32 + qq * 8;
    int col = nt * 16 + n15;
    short8 v;
#pragma unroll
    for (int j = 0; j < 8; j++) v[j] = f2bf(W[(size_t)(k0r + j) * NF + col]);
    *(short8*)(dst + (size_t)idx * 8) = v; // coalesced 16B stores
  }

  mol_barrier(&ctr[mol]);

  // ============ Section B: res_mlp (bf16 MFMA 16x16x32) ============
  if (tid == 0) {
    float t = 0.f;
#pragma unroll
    for (int i = 0; i < 16; i++) t += ws[WS_NUMPART + mol * 16 + i];
    bsum_sh = t;
  }
  if (tid < 128) vsh[tid] = cpos ? v_plus[tid] : v_minus[tid];
  __syncthreads();
  if (tid < 64) awsh[tid] = ch * num_sh[tid] / bsum_sh;

  short* wf = (short*)big;                  // 32 KB
  short* a2s = (short*)(big + 32768);       // 17408 B, [m][k] padded 136
  {
    const float4* src = (const float4*)(ws + WS_FRAG1);
    float4* dst = (float4*)wf;
#pragma unroll
    for (int r = 0; r < 8; r++) dst[tid + r * 256] = src[tid + r * 256];
  }
  __syncthreads();

  int q = l >> 4, l15 = l & 15;
  float aw_m = awsh[w * 16 + l15];
  floatx4 acc1[8];
#pragma unroll
  for (int nt = 0; nt < 8; nt++) acc1[nt] = (floatx4)(0.f);

  // GEMM1: h1 = silu(aw*v) @ Wr1 ; A built in registers
#pragma unroll
  for (int ks = 0; ks < 4; ks++) {
    float4 va = *(const float4*)&vsh[ks * 32 + q * 8];
    float4 vb = *(const float4*)&vsh[ks * 32 + q * 8 + 4];
    short8 af;
    af[0] = f2bf(silu_f(aw_m * va.x)); af[1] = f2bf(silu_f(aw_m * va.y));
    af[2] = f2bf(silu_f(aw_m * va.z)); af[3] = f2bf(silu_f(aw_m * va.w));
    af[4] = f2bf(silu_f(aw_m * vb.x)); af[5] = f2bf(silu_f(aw_m * vb.y));
    af[6] = f2bf(silu_f(aw_m * vb.z)); af[7] = f2bf(silu_f(aw_m * vb.w));
#pragma unroll
    for (int nt = 0; nt < 8; nt++) {
      short8 bf = *(const short8*)&wf[(nt * 4 + ks) * 512 + l * 8];
      acc1[nt] = __builtin_amdgcn_mfma_f32_16x16x32_bf16(af, bf, acc1[nt], 0, 0, 0);
    }
  }

  // silu(h1) -> LDS bf16 [m][k]; C/D layout: row=q*4+r, col=l15
#pragma unroll
  for (int nt = 0; nt < 8; nt++) {
    int f = nt * 16 + l15;
#pragma unroll
    for (int r = 0; r < 4; r++)
      a2s[w * 2176 + (q * 4 + r) * 136 + f] = f2bf(silu_f(acc1[nt][r]));
  }
  __syncthreads();
  {
    const float4* src = (const float4*)(ws + WS_FRAG2);
    float4* dst = (float4*)wf;
#pragma unroll
    for (int r = 0; r < 8; r++) dst[tid + r * 256] = src[tid + r * 256];
  }
  __syncthreads();

  floatx4 acc2[8];
#pragma unroll
  for (int nt = 0; nt < 8; nt++) acc2[nt] = (floatx4)(0.f);

  // GEMM2: h2 = silu(h1) @ Wr2
#pragma unroll
  for (int ks = 0; ks < 4; ks++) {
    short8 af = *(const short8*)&a2s[w * 2176 + l15 * 136 + ks * 32 + q * 8];
#pragma unroll
    for (int nt = 0; nt < 8; nt++) {
      short8 bf = *(const short8*)&wf[(nt * 4 + ks) * 512 + l * 8];
      acc2[nt] = __builtin_amdgcn_mfma_f32_16x16x32_bf16(af, bf, acc2[nt], 0, 0, 0);
    }
  }

  // epilogue: pred = silu(x + h2) . wout_we + e_z.w_e + q_z_table[z]
  float awq[4], part[4];
#pragma unroll
  for (int r = 0; r < 4; r++) {
    awq[r] = awsh[w * 16 + q * 4 + r];
    part[r] = 0.f;
  }
#pragma unroll
  for (int nt = 0; nt < 8; nt++) {
    int f = nt * 16 + l15;
    float vv = vsh[f], ww2 = wout_sh[f];
#pragma unroll
    for (int r = 0; r < 4; r++) {
      float sfl = silu_f(fmaf(awq[r], vv, acc2[nt][r]));
      part[r] = fmaf(sfl, ww2, part[r]);
    }
  }
#pragma unroll
  for (int r = 0; r < 4; r++) {
#pragma unroll
    for (int o = 1; o < 16; o <<= 1) part[r] += __shfl_xor(part[r], o, 64);
  }
  float* pred_shf = (float*)(big + 32768);  // overlay a2s (done with it)
  __syncthreads();
  if (l15 == 0) {
#pragma unroll
    for (int r = 0; r < 4; r++) {
      int m = w * 16 + q * 4 + r;
      int n = base + m;
      float pred = part[r] + ezwe_sh[m] + qz_table[z[n]];
      ws[WS_PRED + n] = pred;
      pred_shf[m] = pred;
    }
  }
  __syncthreads();
  if (tid < 64) {
    float ssum = wave_sum(pred_shf[tid]);
    if (tid == 0) ws[WS_PREDPART + bx] = ssum;
  }

  mol_barrier(&ctr[32 + mol]);

  // ============ Section C: triangle-decomposed switched Coulomb ============
  if (tid == 0) {
    float t = 0.f;
#pragma unroll
    for (int i = 0; i < 16; i++) t += ws[WS_PREDPART + mol * 16 + i];
    bsum_sh = t;
  }
  __syncthreads();
  float corr = (ch - bsum_sh) * (1.f / 1024.f);
  float4* posq = (float4*)big;              // overlay, 16 KB
  const float4* spos = (const float4*)(ws + WS_SPOS);
  const int* sidx = (const int*)(ws + WS_SIDX);
  for (int j = tid; j < 1024; j += 256) {
    float4 p = spos[mol * 1024 + j];
    p.w = ws[WS_PRED + mol * 1024 + sidx[mol * 1024 + j]] + corr;
    posq[j] = p;
  }
  __syncthreads();
  int i = s * 64 + l;
  float4 me = posq[i];
  float e = 0.f;
  for (int c = s + w; c < 16; c += 4) {
    int j0 = c * 64;
    if (c == s) {                           // diagonal chunk: mask j <= i
#pragma unroll 4
      for (int j = j0; j < j0 + 64; j++) {
        float4 p = posq[j];
        float dx = me.x - p.x, dy = me.y - p.y, dz = me.z - p.z;
        float r2 = fmaf(dx, dx, fmaf(dy, dy, dz * dz));
        bool skip = (j <= i);
        float r2s = skip ? 1.0e8f : r2;
        float qj = skip ? 0.f : p.w;
        float inv_r = fast_rsq(r2s);
        e = fmaf(qj, inv_r, e);
        if (__any(r2s < 14.0625f)) {        // R_OFF^2
          float r = r2s * inv_r;
          float arg = (r - 1.25f) * 0.4f;
          float argc = fminf(fmaxf(arg, 1e-6f), 1.f - 1e-6f);
          float t = fast_rcp(argc) - fast_rcp(1.f - argc);
          float fs = fast_rcp(1.f + __expf(-t));
          float delta = fs * (fast_rsq(r2s + 1.f) - inv_r);
          e = fmaf(qj, delta, e);
        }
      }
    } else {
#pragma unroll 4
      for (int j = j0; j < j0 + 64; j++) {
        float4 p = posq[j];
        float dx = me.x - p.x, dy = me.y - p.y, dz = me.z - p.z;
        float r2 = fmaf(dx, dx, fmaf(dy, dy, dz * dz));
        float qj = p.w;
        float inv_r = fast_rsq(r2);
        e = fmaf(qj, inv_r, e);
        if (__any(r2 < 14.0625f)) {
          float r = r2 * inv_r;
          float arg = (r - 1.25f) * 0.4f;
          float argc = fminf(fmaxf(arg, 1e-6f), 1.f - 1e-6f);
          float t = fast_rcp(argc) - fast_rcp(1.f - argc);
          float fs = fast_rcp(1.f + __expf(-t));
          float delta = fs * (fast_rsq(r2 + 1.f) - inv_r);
          e = fmaf(qj, delta, e);
        }
      }
    }
  }
  e *= me.w;
  float sred = wave_sum(e);
  if (l == 0) awsh[w] = sred;               // reuse awsh as 4-float scratch
  __syncthreads();
  if (tid == 0)
    atomicAdd(&out[mol], 332.0636f * (awsh[0] + awsh[1] + awsh[2] + awsh[3]));
}

extern "C" void kernel_launch(void* const* d_in, const int* in_sizes, int n_in,
                              void* d_out, int out_size, void* d_ws, size_t ws_size,
                              hipStream_t stream) {
  const float* e_z     = (const float*)d_in[0];
  const float* charge  = (const float*)d_in[1];
  const float* xyz     = (const float*)d_in[2];
  const float* W_lin   = (const float*)d_in[3];
  const float* b_lin   = (const float*)d_in[4];
  const float* k_plus  = (const float*)d_in[5];
  const float* k_minus = (const float*)d_in[6];
  const float* v_plus  = (const float*)d_in[7];
  const float* v_minus = (const float*)d_in[8];
  const float* Wr1     = (const float*)d_in[9];
  const float* Wr2     = (const float*)d_in[10];
  const float* Wout    = (const float*)d_in[11];
  const float* w_e     = (const float*)d_in[12];
  const float* qz      = (const float*)d_in[13];
  const int*   z       = (const int*)d_in[14];
  float* out = (float*)d_out;
  float* ws  = (float*)d_ws;

  hipMemsetAsync(ws + WS_CTR, 0, 64 * sizeof(unsigned), stream);
  hipMemsetAsync(out, 0, B_MOL * sizeof(float), stream);
  fused_kernel<<<512, 256, 0, stream>>>(e_z, charge, xyz, W_lin, b_lin,
                                        k_plus, k_minus, v_plus, v_minus,
                                        Wr1, Wr2, Wout, w_e, qz, z, ws, out);
}

// Round 8
// 154.349 us; speedup vs baseline: 2.1196x; 1.5400x over previous
//
#include <hip/hip_runtime.h>
#include <math.h>

#define B_MOL 32
#define A_AT  1024
#define NF    128
#define N_AT  (B_MOL * A_AT)

// workspace layout (float offsets)
#define WS_NUMSUM   512       // 32 floats (memset 0) — atomicAdd'ed, atomic-read
#define WS_PREDSUM  544       // 32 floats (memset 0) — crosses K1->K2 boundary
#define WS_PRED     16384     // float[N_AT]           — crosses K1->K2 boundary
#define WS_SIDX     49152     // int[N_AT] sorted->orig
#define WS_SPOS     81920     // float4[N_AT] sorted positions
#define WS_CTR      214528    // uint[32*16] barrier ctr, stride 16 (64B) per mol (memset 0)

typedef short short8 __attribute__((ext_vector_type(8)));
typedef float floatx4 __attribute__((ext_vector_type(4)));

__device__ __forceinline__ float fast_rcp(float x) { return __builtin_amdgcn_rcpf(x); }
__device__ __forceinline__ float fast_rsq(float x) { return __builtin_amdgcn_rsqf(x); }
__device__ __forceinline__ float silu_f(float x) { return x * fast_rcp(1.f + __expf(-x)); }

__device__ __forceinline__ short f2bf(float x) {   // RNE f32 -> bf16
  unsigned u = __float_as_uint(x);
  u += 0x7fffu + ((u >> 16) & 1u);
  return (short)(u >> 16);
}

__device__ __forceinline__ float wave_sum(float v) {
#pragma unroll
  for (int o = 32; o > 0; o >>= 1) v += __shfl_xor(v, o, 64);
  return v;
}

// ============ K1: attn + sort + atomic-only numsum barrier + MFMA mlp ============
// gfx950 lesson (R5-R7): NO __threadfence anywhere. Device-scope wb/inv ops
// (~2000 of them) serialized the chip at ~150us regardless of poll flavor.
// Scalars cross the in-kernel barrier purely via atomic RMWs (coherence-point
// ops, no cache maintenance); bulk data (pred, sort) crosses the K1->K2
// kernel boundary, where the HW handles coherence.
__global__ __launch_bounds__(256, 2) void attn_mlp_kernel(
    const float* __restrict__ e_z, const float* __restrict__ charge,
    const float* __restrict__ xyz, const float* __restrict__ W_lin,
    const float* __restrict__ b_lin, const float* __restrict__ k_plus,
    const float* __restrict__ k_minus, const float* __restrict__ v_plus,
    const float* __restrict__ v_minus, const float* __restrict__ Wr1,
    const float* __restrict__ Wr2, const float* __restrict__ Wout,
    const float* __restrict__ w_e, const float* __restrict__ qz_table,
    const int* __restrict__ z, float* __restrict__ ws) {
  int bx = blockIdx.x, tid = threadIdx.x;
  int mol = bx >> 4, s = bx & 15;
  int base = bx * 64;                       // = mol*1024 + s*64

  __shared__ __align__(16) char big[50176]; // A: k2/wesh/hist ; B: wf(32K)+a2s(17K)
  __shared__ float num_sh[64], ezwe_sh[64], wout_sh[128], awsh[64], vsh[128];
  __shared__ float cc_sh, bsum_sh;

  float* k2 = (float*)big;                  // [128]
  float* wesh = k2 + 128;                   // [128]
  int* hist = (int*)(wesh + 128);           // [64]
  int* startc = hist + 64;                  // [64]
  float* numred = (float*)(startc + 64);    // [4]
  unsigned* ctr = (unsigned*)(ws + WS_CTR) + mol * 16;   // 64B apart per molecule

  float ch = charge[mol];
  bool cpos = ch >= 0.f;
  const float* kvec = cpos ? k_plus : k_minus;

  // ---- A1: k2 = W_lin @ kvec (t0-127) ; wout_we = Wout @ w_e (t128-255)
  {
    int r = tid & 127;
    const float* M = (tid < 128) ? W_lin : Wout;
    const float* vv = (tid < 128) ? kvec : w_e;
    const float4* row = (const float4*)(M + (size_t)r * NF);
    float acc = 0.f;
#pragma unroll 8
    for (int i = 0; i < 32; i++) {
      float4 a = row[i];
      float4 b = ((const float4*)vv)[i];
      acc = fmaf(a.x, b.x, acc); acc = fmaf(a.y, b.y, acc);
      acc = fmaf(a.z, b.z, acc); acc = fmaf(a.w, b.w, acc);
    }
    if (tid < 128) { k2[r] = acc; wesh[r] = w_e[r]; }
    else wout_sh[r] = acc;
  }
  if (tid < 64) {
    float c = b_lin[tid] * kvec[tid] + b_lin[tid + 64] * kvec[tid + 64];
    c = wave_sum(c);
    if (tid == 0) cc_sh = c;
  }
  __syncthreads();

  // ---- A2: attn for own 64 atoms (num/ezwe stay in LDS)
  int w = tid >> 6, l = tid & 63, half = l >> 5, l31 = l & 31;
  {
    int b4 = l31 * 4;
    float ka = k2[b4], kb = k2[b4 + 1], kc = k2[b4 + 2], kd = k2[b4 + 3];
    float wa = wesh[b4], wb = wesh[b4 + 1], wc = wesh[b4 + 2], wd = wesh[b4 + 3];
    float cc = cc_sh;
    float wavenum = 0.f;
#pragma unroll
    for (int it = 0; it < 8; it++) {
      int m = it * 8 + w * 2 + half;
      int n = base + m;
      float4 v = *((const float4*)(e_z + (size_t)n * NF) + l31);  // coalesced
      float dk = v.x * ka; dk = fmaf(v.y, kb, dk); dk = fmaf(v.z, kc, dk); dk = fmaf(v.w, kd, dk);
      float dw = v.x * wa; dw = fmaf(v.y, wb, dw); dw = fmaf(v.z, wc, dw); dw = fmaf(v.w, wd, dw);
#pragma unroll
      for (int o = 1; o < 32; o <<= 1) {
        dk += __shfl_xor(dk, o, 64);
        dw += __shfl_xor(dw, o, 64);
      }
      if (l31 == 0) {
        float arg = (dk + cc) * 0.08838834764831845f;   // 1/sqrt(128)
        float num = fmaxf(arg, 0.f) + log1pf(__expf(-fabsf(arg)));
        num_sh[m] = num;
        ezwe_sh[m] = dw;
        wavenum += num;
      }
    }
    wavenum += __shfl_xor(wavenum, 32, 64);
    if (l == 0) numred[w] = wavenum;
  }
  __syncthreads();
  if (tid == 0)
    atomicAdd(&ws[WS_NUMSUM + mol], numred[0] + numred[1] + numred[2] + numred[3]);

  // ---- A3 (s==0): spatial counting sort (output consumed only by K2)
  if (s == 0) {
    if (tid < 64) hist[tid] = 0;
    __syncthreads();
    float px[4], py[4], pz[4];
    int cell[4];
#pragma unroll
    for (int r = 0; r < 4; r++) {
      int j = tid + r * 256;
      const float* p = xyz + (size_t)(mol * A_AT + j) * 3;
      px[r] = p[0]; py[r] = p[1]; pz[r] = p[2];
      int cx = min(3, max(0, (int)(px[r] * (4.f / 22.f))));
      int cy = min(3, max(0, (int)(py[r] * (4.f / 22.f))));
      int cz = min(3, max(0, (int)(pz[r] * (4.f / 22.f))));
      cell[r] = cx * 16 + cy * 4 + cz;
      atomicAdd(&hist[cell[r]], 1);
    }
    __syncthreads();
    if (tid == 0) {
      int acc = 0;
      for (int c = 0; c < 64; c++) { startc[c] = acc; acc += hist[c]; }
    }
    __syncthreads();
    float4* spos = (float4*)(ws + WS_SPOS);
    int* sidx = (int*)(ws + WS_SIDX);
#pragma unroll
    for (int r = 0; r < 4; r++) {
      int j = tid + r * 256;
      int off = atomicAdd(&startc[cell[r]], 1);
      int g = mol * A_AT + off;
      spos[g] = make_float4(px[r], py[r], pz[r], 0.f);
      sidx[g] = j;
    }
  }

  // ---- barrier-1: atomic-only (no fences). __syncthreads above+here drains
  // vmcnt, so this block's numsum atomicAdd completed before the ctr bump.
  __syncthreads();
  if (tid == 0) {
    __hip_atomic_fetch_add(ctr, 1u, __ATOMIC_RELAXED, __HIP_MEMORY_SCOPE_AGENT);
    while (__hip_atomic_fetch_add(ctr, 0u, __ATOMIC_RELAXED,
                                  __HIP_MEMORY_SCOPE_AGENT) < 16u)
      __builtin_amdgcn_s_sleep(8);
    // read the molecule sum with an RMW (coherence-point read, no fence)
    bsum_sh = __hip_atomic_fetch_add(&ws[WS_NUMSUM + mol], 0.0f,
                                     __ATOMIC_RELAXED, __HIP_MEMORY_SCOPE_AGENT);
  }
  if (tid < 128) vsh[tid] = cpos ? v_plus[tid] : v_minus[tid];
  __syncthreads();
  if (tid < 64) awsh[tid] = ch * num_sh[tid] / bsum_sh;

  // ---- B: res_mlp. Weight frags gathered straight from global (L2-broadcast)
  // into LDS, swizzled on the fly — nothing bulk crossed the barrier.
  // Frag fi=nt*4+ks, lane q*16+n15 holds B[k=ks*32+q*8+j][n=nt*16+n15], j=0..7.
  short* wf = (short*)big;                  // 32 KB
  short* a2s = (short*)(big + 32768);       // 17408 B, [m][k] padded 136
#pragma unroll
  for (int e = 0; e < 8; e++) {
    int idx = e * 256 + tid;
    int fi = idx >> 6, ln = idx & 63;
    int nt = fi >> 2, ks = fi & 3;
    const float* src = Wr1 + (size_t)(ks * 32 + (ln >> 4) * 8) * NF + nt * 16 + (ln & 15);
    short8 v;
#pragma unroll
    for (int j = 0; j < 8; j++) v[j] = f2bf(src[j * NF]);
    *(short8*)&wf[idx * 8] = v;
  }
  __syncthreads();

  int q = l >> 4, l15 = l & 15;
  float aw_m = awsh[w * 16 + l15];
  floatx4 acc1[8];
#pragma unroll
  for (int nt = 0; nt < 8; nt++) acc1[nt] = (floatx4)(0.f);

  // GEMM1: h1 = silu(aw*v) @ Wr1 ; A built in registers
#pragma unroll
  for (int ks = 0; ks < 4; ks++) {
    float4 va = *(const float4*)&vsh[ks * 32 + q * 8];
    float4 vb = *(const float4*)&vsh[ks * 32 + q * 8 + 4];
    short8 af;
    af[0] = f2bf(silu_f(aw_m * va.x)); af[1] = f2bf(silu_f(aw_m * va.y));
    af[2] = f2bf(silu_f(aw_m * va.z)); af[3] = f2bf(silu_f(aw_m * va.w));
    af[4] = f2bf(silu_f(aw_m * vb.x)); af[5] = f2bf(silu_f(aw_m * vb.y));
    af[6] = f2bf(silu_f(aw_m * vb.z)); af[7] = f2bf(silu_f(aw_m * vb.w));
#pragma unroll
    for (int nt = 0; nt < 8; nt++) {
      short8 bf = *(const short8*)&wf[(nt * 4 + ks) * 512 + l * 8];
      acc1[nt] = __builtin_amdgcn_mfma_f32_16x16x32_bf16(af, bf, acc1[nt], 0, 0, 0);
    }
  }

  // silu(h1) -> LDS bf16 [m][k]; C/D layout: row=q*4+r, col=l15
#pragma unroll
  for (int nt = 0; nt < 8; nt++) {
    int f = nt * 16 + l15;
#pragma unroll
    for (int r = 0; r < 4; r++)
      a2s[w * 2176 + (q * 4 + r) * 136 + f] = f2bf(silu_f(acc1[nt][r]));
  }
  __syncthreads();
  // restage Wr2 frags (wf reads of GEMM1 are done — barrier above)
#pragma unroll
  for (int e = 0; e < 8; e++) {
    int idx = e * 256 + tid;
    int fi = idx >> 6, ln = idx & 63;
    int nt = fi >> 2, ks = fi & 3;
    const float* src = Wr2 + (size_t)(ks * 32 + (ln >> 4) * 8) * NF + nt * 16 + (ln & 15);
    short8 v;
#pragma unroll
    for (int j = 0; j < 8; j++) v[j] = f2bf(src[j * NF]);
    *(short8*)&wf[idx * 8] = v;
  }
  __syncthreads();

  floatx4 acc2[8];
#pragma unroll
  for (int nt = 0; nt < 8; nt++) acc2[nt] = (floatx4)(0.f);

  // GEMM2: h2 = silu(h1) @ Wr2
#pragma unroll
  for (int ks = 0; ks < 4; ks++) {
    short8 af = *(const short8*)&a2s[w * 2176 + l15 * 136 + ks * 32 + q * 8];
#pragma unroll
    for (int nt = 0; nt < 8; nt++) {
      short8 bf = *(const short8*)&wf[(nt * 4 + ks) * 512 + l * 8];
      acc2[nt] = __builtin_amdgcn_mfma_f32_16x16x32_bf16(af, bf, acc2[nt], 0, 0, 0);
    }
  }

  // epilogue: pred = silu(x + h2) . wout_we + e_z.w_e + q_z_table[z]
  float awq[4], part[4];
#pragma unroll
  for (int r = 0; r < 4; r++) {
    awq[r] = awsh[w * 16 + q * 4 + r];
    part[r] = 0.f;
  }
#pragma unroll
  for (int nt = 0; nt < 8; nt++) {
    int f = nt * 16 + l15;
    float vv = vsh[f], ww2 = wout_sh[f];
#pragma unroll
    for (int r = 0; r < 4; r++) {
      float sfl = silu_f(fmaf(awq[r], vv, acc2[nt][r]));
      part[r] = fmaf(sfl, ww2, part[r]);
    }
  }
#pragma unroll
  for (int r = 0; r < 4; r++) {
#pragma unroll
    for (int o = 1; o < 16; o <<= 1) part[r] += __shfl_xor(part[r], o, 64);
  }
  float* pred_shf = (float*)(big + 32768);  // overlay a2s (done with it)
  __syncthreads();
  if (l15 == 0) {
#pragma unroll
    for (int r = 0; r < 4; r++) {
      int m = w * 16 + q * 4 + r;
      int n = base + m;
      float pred = part[r] + ezwe_sh[m] + qz_table[z[n]];
      ws[WS_PRED + n] = pred;                // plain store; K2 reads post-boundary
      pred_shf[m] = pred;
    }
  }
  __syncthreads();
  if (tid < 64) {
    float ssum = wave_sum(pred_shf[tid]);
    if (tid == 0) atomicAdd(&ws[WS_PREDSUM + mol], ssum);
  }
}

// ============ K2: triangle-decomposed switched Coulomb (R4-proven) ============
__global__ __launch_bounds__(256) void pair_kernel(const float* __restrict__ charge,
                                                   float* __restrict__ ws,
                                                   float* __restrict__ out) {
  int bx = blockIdx.x;         // 512 = 32 mol * 16 i-chunks
  int mol = bx >> 4;
  int s = bx & 15;
  int tid = threadIdx.x;
  int w = tid >> 6, lane = tid & 63;
  __shared__ float4 posq[1024];   // 16 KB
  __shared__ float wred[4];
  const float4* spos = (const float4*)(ws + WS_SPOS);
  const int* sidx = (const int*)(ws + WS_SIDX);
  float corr = (charge[mol] - ws[WS_PREDSUM + mol]) * (1.f / 1024.f);
  for (int j = tid; j < 1024; j += 256) {
    float4 p = spos[mol * 1024 + j];
    p.w = ws[WS_PRED + mol * 1024 + sidx[mol * 1024 + j]] + corr;
    posq[j] = p;
  }
  __syncthreads();
  int i = s * 64 + lane;
  float4 me = posq[i];
  float e = 0.f;
  for (int c = s + w; c < 16; c += 4) {
    int j0 = c * 64;
    if (c == s) {                           // diagonal chunk: mask j <= i
#pragma unroll 4
      for (int j = j0; j < j0 + 64; j++) {
        float4 p = posq[j];
        float dx = me.x - p.x, dy = me.y - p.y, dz = me.z - p.z;
        float r2 = fmaf(dx, dx, fmaf(dy, dy, dz * dz));
        bool skip = (j <= i);
        float r2s = skip ? 1.0e8f : r2;
        float qj = skip ? 0.f : p.w;
        float inv_r = fast_rsq(r2s);
        e = fmaf(qj, inv_r, e);
        if (__any(r2s < 14.0625f)) {        // R_OFF^2
          float r = r2s * inv_r;
          float arg = (r - 1.25f) * 0.4f;
          float argc = fminf(fmaxf(arg, 1e-6f), 1.f - 1e-6f);
          float t = fast_rcp(argc) - fast_rcp(1.f - argc);
          float fs = fast_rcp(1.f + __expf(-t));
          float delta = fs * (fast_rsq(r2s + 1.f) - inv_r);
          e = fmaf(qj, delta, e);
        }
      }
    } else {
#pragma unroll 4
      for (int j = j0; j < j0 + 64; j++) {
        float4 p = posq[j];
        float dx = me.x - p.x, dy = me.y - p.y, dz = me.z - p.z;
        float r2 = fmaf(dx, dx, fmaf(dy, dy, dz * dz));
        float qj = p.w;
        float inv_r = fast_rsq(r2);
        e = fmaf(qj, inv_r, e);
        if (__any(r2 < 14.0625f)) {
          float r = r2 * inv_r;
          float arg = (r - 1.25f) * 0.4f;
          float argc = fminf(fmaxf(arg, 1e-6f), 1.f - 1e-6f);
          float t = fast_rcp(argc) - fast_rcp(1.f - argc);
          float fs = fast_rcp(1.f + __expf(-t));
          float delta = fs * (fast_rsq(r2 + 1.f) - inv_r);
          e = fmaf(qj, delta, e);
        }
      }
    }
  }
  e *= me.w;
  float sred = wave_sum(e);
  if (lane == 0) wred[w] = sred;
  __syncthreads();
  if (tid == 0)
    atomicAdd(&out[mol], 332.0636f * (wred[0] + wred[1] + wred[2] + wred[3]));
}

extern "C" void kernel_launch(void* const* d_in, const int* in_sizes, int n_in,
                              void* d_out, int out_size, void* d_ws, size_t ws_size,
                              hipStream_t stream) {
  const float* e_z     = (const float*)d_in[0];
  const float* charge  = (const float*)d_in[1];
  const float* xyz     = (const float*)d_in[2];
  const float* W_lin   = (const float*)d_in[3];
  const float* b_lin   = (const float*)d_in[4];
  const float* k_plus  = (const float*)d_in[5];
  const float* k_minus = (const float*)d_in[6];
  const float* v_plus  = (const float*)d_in[7];
  const float* v_minus = (const float*)d_in[8];
  const float* Wr1     = (const float*)d_in[9];
  const float* Wr2     = (const float*)d_in[10];
  const float* Wout    = (const float*)d_in[11];
  const float* w_e     = (const float*)d_in[12];
  const float* qz      = (const float*)d_in[13];
  const int*   z       = (const int*)d_in[14];
  float* out = (float*)d_out;
  float* ws  = (float*)d_ws;

  hipMemsetAsync(ws + WS_NUMSUM, 0, 64 * sizeof(float), stream);   // numsum+predsum
  hipMemsetAsync(ws + WS_CTR, 0, 512 * sizeof(unsigned), stream);  // barrier ctrs
  hipMemsetAsync(out, 0, B_MOL * sizeof(float), stream);
  attn_mlp_kernel<<<512, 256, 0, stream>>>(e_z, charge, xyz, W_lin, b_lin,
                                           k_plus, k_minus, v_plus, v_minus,
                                           Wr1, Wr2, Wout, w_e, qz, z, ws);
  pair_kernel<<<512, 256, 0, stream>>>(charge, ws, out);
}

// Round 9
// 136.786 us; speedup vs baseline: 2.3918x; 1.1284x over previous
//
#include <hip/hip_runtime.h>
#include <math.h>

#define B_MOL 32
#define A_AT  1024
#define NF    128
#define N_AT  (B_MOL * A_AT)

// workspace layout (float offsets) — no counters, no accumulators, no memsets
#define WS_FRAG1    0         // short[16384]: Wr1 bf16 MFMA-B frags
#define WS_FRAG2    8192      // short[16384]: Wr2 frags
#define WS_WOUT     16384     // float[128]: Wout @ w_e
#define WS_NUM      16512     // float[N_AT]: softplus(arg), orig order
#define WS_EZWE     49280     // float[N_AT]: e_z . w_e, orig order
#define WS_PREDS    82048     // float[N_AT]: pred_q in SORTED order
#define WS_IINV     114816    // int[N_AT]: orig -> sorted index
#define WS_SPOS     147584    // float4[N_AT]: sorted positions

typedef short short8 __attribute__((ext_vector_type(8)));
typedef float floatx4 __attribute__((ext_vector_type(4)));

__device__ __forceinline__ float fast_rcp(float x) { return __builtin_amdgcn_rcpf(x); }
__device__ __forceinline__ float fast_rsq(float x) { return __builtin_amdgcn_rsqf(x); }
__device__ __forceinline__ float silu_f(float x) { return x * fast_rcp(1.f + __expf(-x)); }

__device__ __forceinline__ short f2bf(float x) {   // RNE f32 -> bf16
  unsigned u = __float_as_uint(x);
  u += 0x7fffu + ((u >> 16) & 1u);
  return (short)(u >> 16);
}

__device__ __forceinline__ float wave_sum(float v) {
#pragma unroll
  for (int o = 32; o > 0; o >>= 1) v += __shfl_xor(v, o, 64);
  return v;
}

// ============ K1: attn + sort + (mol0) weight swizzle / wout / out-zero ============
// gfx950 lesson (R5-R8): the kernel boundary is the ONLY cheap cross-block sync.
// No barriers, no fences, no global atomics in this program.
__global__ __launch_bounds__(256) void attn_sort_kernel(
    const float* __restrict__ e_z, const float* __restrict__ charge,
    const float* __restrict__ xyz, const float* __restrict__ W_lin,
    const float* __restrict__ b_lin, const float* __restrict__ k_plus,
    const float* __restrict__ k_minus, const float* __restrict__ Wr1,
    const float* __restrict__ Wr2, const float* __restrict__ Wout,
    const float* __restrict__ w_e, float* __restrict__ ws,
    float* __restrict__ out) {
  int bx = blockIdx.x, tid = threadIdx.x;
  int mol = bx >> 4, s = bx & 15;
  int base = bx * 64;

  __shared__ float k2[NF], wesh[NF];
  __shared__ int hist[64], startc[64];
  __shared__ float cc_sh;

  float ch = charge[mol];
  const float* kvec = (ch >= 0.f) ? k_plus : k_minus;

  // k2[r] = W_lin[r,:] . kvec (each block, redundant but parallel, L2-hot)
  if (tid < 128) {
    const float4* row = (const float4*)(W_lin + (size_t)tid * NF);
    float acc = 0.f;
#pragma unroll 8
    for (int i = 0; i < 32; i++) {
      float4 a = row[i];
      float4 b = ((const float4*)kvec)[i];
      acc = fmaf(a.x, b.x, acc); acc = fmaf(a.y, b.y, acc);
      acc = fmaf(a.z, b.z, acc); acc = fmaf(a.w, b.w, acc);
    }
    k2[tid] = acc;
    wesh[tid] = w_e[tid];
  }
  if (tid < 64) {
    float c = b_lin[tid] * kvec[tid] + b_lin[tid + 64] * kvec[tid + 64];
    c = wave_sum(c);
    if (tid == 0) cc_sh = c;
  }
  __syncthreads();

  // attn for own 64 atoms -> ws[WS_NUM/WS_EZWE] (plain stores; K2 reads post-boundary)
  int w = tid >> 6, l = tid & 63, half = l >> 5, l31 = l & 31;
  {
    int b4 = l31 * 4;
    float ka = k2[b4], kb = k2[b4 + 1], kc = k2[b4 + 2], kd = k2[b4 + 3];
    float wa = wesh[b4], wb = wesh[b4 + 1], wc = wesh[b4 + 2], wd = wesh[b4 + 3];
    float cc = cc_sh;
#pragma unroll
    for (int it = 0; it < 8; it++) {
      int m = it * 8 + w * 2 + half;
      int n = base + m;
      float4 v = *((const float4*)(e_z + (size_t)n * NF) + l31);  // coalesced 1KB/wave
      float dk = v.x * ka; dk = fmaf(v.y, kb, dk); dk = fmaf(v.z, kc, dk); dk = fmaf(v.w, kd, dk);
      float dw = v.x * wa; dw = fmaf(v.y, wb, dw); dw = fmaf(v.z, wc, dw); dw = fmaf(v.w, wd, dw);
#pragma unroll
      for (int o = 1; o < 32; o <<= 1) {
        dk += __shfl_xor(dk, o, 64);
        dw += __shfl_xor(dw, o, 64);
      }
      if (l31 == 0) {
        float arg = (dk + cc) * 0.08838834764831845f;   // 1/sqrt(128)
        ws[WS_NUM + n] = fmaxf(arg, 0.f) + log1pf(__expf(-fabsf(arg)));
        ws[WS_EZWE + n] = dw;
      }
    }
  }

  if (s == 0) {
    // spatial counting sort, 4x4x4 cells of 5.5 A; emits sorted pos + inverse map
    if (tid < 64) hist[tid] = 0;
    __syncthreads();
    float px[4], py[4], pz[4];
    int cell[4];
#pragma unroll
    for (int r = 0; r < 4; r++) {
      int j = tid + r * 256;
      const float* p = xyz + (size_t)(mol * A_AT + j) * 3;
      px[r] = p[0]; py[r] = p[1]; pz[r] = p[2];
      int cx = min(3, max(0, (int)(px[r] * (4.f / 22.f))));
      int cy = min(3, max(0, (int)(py[r] * (4.f / 22.f))));
      int cz = min(3, max(0, (int)(pz[r] * (4.f / 22.f))));
      cell[r] = cx * 16 + cy * 4 + cz;
      atomicAdd(&hist[cell[r]], 1);
    }
    __syncthreads();
    if (tid == 0) {
      int acc = 0;
      for (int c = 0; c < 64; c++) { startc[c] = acc; acc += hist[c]; }
    }
    __syncthreads();
    float4* spos = (float4*)(ws + WS_SPOS);
    int* iinv = (int*)ws + WS_IINV;
#pragma unroll
    for (int r = 0; r < 4; r++) {
      int j = tid + r * 256;
      int off = atomicAdd(&startc[cell[r]], 1);
      spos[mol * A_AT + off] = make_float4(px[r], py[r], pz[r], 0.f);
      iinv[mol * A_AT + j] = mol * A_AT + off;
    }
  } else if (mol == 0 && (s == 1 || s == 2)) {
    // swizzle Wr1/Wr2 into bf16 MFMA-B frag order (coalesced float4 reads).
    // Frag fi=nt*4+ks, lane q*16+n15 holds B[k=ks*32+q*8+j][n=nt*16+n15].
    const float* W = (s == 1) ? Wr1 : Wr2;
    short* dst = (short*)(ws + ((s == 1) ? WS_FRAG1 : WS_FRAG2));
#pragma unroll
    for (int it = 0; it < 16; it++) {
      int idx = it * 256 + tid;        // float4 index over 128x128
      int k = idx >> 5;
      int c0 = (idx & 31) * 4;
      float4 v = ((const float4*)W)[idx];
      int ks = k >> 5, q = (k & 31) >> 3, j = k & 7;
      float vv[4] = {v.x, v.y, v.z, v.w};
#pragma unroll
      for (int e = 0; e < 4; e++) {
        int col = c0 + e;
        int fi = (col >> 4) * 4 + ks;
        int lane = q * 16 + (col & 15);
        dst[fi * 512 + lane * 8 + j] = f2bf(vv[e]);
      }
    }
  } else if (mol == 0 && s == 3) {
    if (tid < 128) {
      float sw = 0.f;
      for (int f = 0; f < NF; f++) sw = fmaf(Wout[tid * NF + f], w_e[f], sw);
      ws[WS_WOUT + tid] = sw;
    }
    if (tid >= 128 && tid < 160) out[tid - 128] = 0.f;   // zero energies
  }
}

// ============ K2: res_mlp (bf16 MFMA 16x16x32), 64 atoms/block ============
__global__ __launch_bounds__(256) void mlp_kernel(
    const float* __restrict__ charge, const float* __restrict__ v_plus,
    const float* __restrict__ v_minus, const int* __restrict__ z,
    const float* __restrict__ qz_table, float* __restrict__ ws) {
  int bx = blockIdx.x, tid = threadIdx.x;
  int mol = bx >> 4;
  int base = bx * 64;
  int w = tid >> 6, l = tid & 63;

  __shared__ __align__(16) short wf[16384];      // 32 KB
  __shared__ short a2s[4 * 16 * 136];            // 17 KB
  __shared__ float vsh[NF], wout_sh[NF], awsh[64], ezwe_sh[64], wred[4];
  __shared__ float numsum_sh;

  float ch = charge[mol];
  // numsum: re-reduce the molecule's 1024 nums in-block (L2-hot, no atomics)
  {
    float4 nv = ((const float4*)(ws + WS_NUM + mol * A_AT))[tid];
    float p = nv.x + nv.y + nv.z + nv.w;
    p = wave_sum(p);
    if (l == 0) wred[w] = p;
  }
  if (tid < 128) {
    vsh[tid] = (ch >= 0.f) ? v_plus[tid] : v_minus[tid];
    wout_sh[tid] = ws[WS_WOUT + tid];
  }
  {  // stage Wr1 frags (coalesced from pre-swizzled ws)
    const float4* src = (const float4*)(ws + WS_FRAG1);
    float4* dst = (float4*)wf;
#pragma unroll
    for (int r = 0; r < 8; r++) dst[tid + r * 256] = src[tid + r * 256];
  }
  __syncthreads();
  if (tid == 0) numsum_sh = wred[0] + wred[1] + wred[2] + wred[3];
  __syncthreads();
  if (tid < 64) {
    awsh[tid] = ch * ws[WS_NUM + base + tid] / numsum_sh;
    ezwe_sh[tid] = ws[WS_EZWE + base + tid];
  }
  __syncthreads();

  int q = l >> 4, l15 = l & 15;
  float aw_m = awsh[w * 16 + l15];
  floatx4 acc1[8];
#pragma unroll
  for (int nt = 0; nt < 8; nt++) acc1[nt] = (floatx4)(0.f);

  // GEMM1: h1 = silu(aw*v) @ Wr1 ; A built in registers
#pragma unroll
  for (int ks = 0; ks < 4; ks++) {
    float4 va = *(const float4*)&vsh[ks * 32 + q * 8];
    float4 vb = *(const float4*)&vsh[ks * 32 + q * 8 + 4];
    short8 af;
    af[0] = f2bf(silu_f(aw_m * va.x)); af[1] = f2bf(silu_f(aw_m * va.y));
    af[2] = f2bf(silu_f(aw_m * va.z)); af[3] = f2bf(silu_f(aw_m * va.w));
    af[4] = f2bf(silu_f(aw_m * vb.x)); af[5] = f2bf(silu_f(aw_m * vb.y));
    af[6] = f2bf(silu_f(aw_m * vb.z)); af[7] = f2bf(silu_f(aw_m * vb.w));
#pragma unroll
    for (int nt = 0; nt < 8; nt++) {
      short8 bf = *(const short8*)&wf[(nt * 4 + ks) * 512 + l * 8];
      acc1[nt] = __builtin_amdgcn_mfma_f32_16x16x32_bf16(af, bf, acc1[nt], 0, 0, 0);
    }
  }

  // silu(h1) -> LDS bf16 [m][k]; C/D layout: row=q*4+r, col=l15
#pragma unroll
  for (int nt = 0; nt < 8; nt++) {
    int f = nt * 16 + l15;
#pragma unroll
    for (int r = 0; r < 4; r++)
      a2s[w * 2176 + (q * 4 + r) * 136 + f] = f2bf(silu_f(acc1[nt][r]));
  }
  __syncthreads();
  {  // restage Wr2 frags
    const float4* src = (const float4*)(ws + WS_FRAG2);
    float4* dst = (float4*)wf;
#pragma unroll
    for (int r = 0; r < 8; r++) dst[tid + r * 256] = src[tid + r * 256];
  }
  __syncthreads();

  floatx4 acc2[8];
#pragma unroll
  for (int nt = 0; nt < 8; nt++) acc2[nt] = (floatx4)(0.f);

  // GEMM2: h2 = silu(h1) @ Wr2
#pragma unroll
  for (int ks = 0; ks < 4; ks++) {
    short8 af = *(const short8*)&a2s[w * 2176 + l15 * 136 + ks * 32 + q * 8];
#pragma unroll
    for (int nt = 0; nt < 8; nt++) {
      short8 bf = *(const short8*)&wf[(nt * 4 + ks) * 512 + l * 8];
      acc2[nt] = __builtin_amdgcn_mfma_f32_16x16x32_bf16(af, bf, acc2[nt], 0, 0, 0);
    }
  }

  // epilogue: pred = silu(x + h2) . wout_we + e_z.w_e + q_z_table[z]
  // scatter-write in SORTED order (64 scatters/block once, K3 stays coalesced)
  float awq[4], part[4];
#pragma unroll
  for (int r = 0; r < 4; r++) {
    awq[r] = awsh[w * 16 + q * 4 + r];
    part[r] = 0.f;
  }
#pragma unroll
  for (int nt = 0; nt < 8; nt++) {
    int f = nt * 16 + l15;
    float vv = vsh[f], ww2 = wout_sh[f];
#pragma unroll
    for (int r = 0; r < 4; r++) {
      float sfl = silu_f(fmaf(awq[r], vv, acc2[nt][r]));
      part[r] = fmaf(sfl, ww2, part[r]);
    }
  }
#pragma unroll
  for (int r = 0; r < 4; r++) {
#pragma unroll
    for (int o = 1; o < 16; o <<= 1) part[r] += __shfl_xor(part[r], o, 64);
  }
  if (l15 == 0) {
    const int* iinv = (const int*)ws + WS_IINV;
#pragma unroll
    for (int r = 0; r < 4; r++) {
      int m = w * 16 + q * 4 + r;
      int n = base + m;
      ws[WS_PREDS + iinv[n]] = part[r] + ezwe_sh[m] + qz_table[z[n]];
    }
  }
}

// ============ K3: balanced wrap-decomposed switched Coulomb ============
// Block (mol,a): i-chunk a vs chunk-distances d=0..7 (+d=8 iff a<8); every
// unordered pair covered exactly once. predsum computed in-block from staged preds.
__global__ __launch_bounds__(256) void pair_kernel(const float* __restrict__ charge,
                                                   const float* __restrict__ ws,
                                                   float* __restrict__ out) {
  int bx = blockIdx.x;
  int mol = bx >> 4;
  int a = bx & 15;
  int tid = threadIdx.x;
  int w = tid >> 6, l = tid & 63;
  __shared__ float4 posq[1024];   // 16 KB
  __shared__ float wred[4];
  const float4* spos = (const float4*)(ws + WS_SPOS);
  const float* preds = ws + WS_PREDS + mol * A_AT;
  float psum = 0.f;
  for (int j = tid; j < 1024; j += 256) {   // fully coalesced staging
    float4 p = spos[mol * A_AT + j];
    p.w = preds[j];
    posq[j] = p;
    psum += p.w;
  }
  psum = wave_sum(psum);
  if (l == 0) wred[w] = psum;
  __syncthreads();
  float corr = (charge[mol] - (wred[0] + wred[1] + wred[2] + wred[3])) * (1.f / 1024.f);
  for (int j = tid; j < 1024; j += 256) posq[j].w += corr;
  __syncthreads();

  int i = a * 64 + l;
  float4 me = posq[i];
  float e = 0.f;
#pragma unroll
  for (int t = 0; t < 2; t++) {
    int d = w + t * 4;                      // wave w: distances {w, w+4}
    int c = (a + d) & 15;
    int j0 = c * 64;
    if (d == 0) {                           // diagonal: mask j <= i
#pragma unroll 4
      for (int j = j0; j < j0 + 64; j++) {
        float4 p = posq[j];
        float dx = me.x - p.x, dy = me.y - p.y, dz = me.z - p.z;
        float r2 = fmaf(dx, dx, fmaf(dy, dy, dz * dz));
        bool skip = (j <= i);
        float r2s = skip ? 1.0e8f : r2;
        float qj = skip ? 0.f : p.w;
        float inv_r = fast_rsq(r2s);
        e = fmaf(qj, inv_r, e);
        if (__any(r2s < 14.0625f)) {        // R_OFF^2
          float r = r2s * inv_r;
          float arg = (r - 1.25f) * 0.4f;
          float argc = fminf(fmaxf(arg, 1e-6f), 1.f - 1e-6f);
          float tt = fast_rcp(argc) - fast_rcp(1.f - argc);
          float fs = fast_rcp(1.f + __expf(-tt));
          float delta = fs * (fast_rsq(r2s + 1.f) - inv_r);
          e = fmaf(qj, delta, e);
        }
      }
    } else {
#pragma unroll 4
      for (int j = j0; j < j0 + 64; j++) {
        float4 p = posq[j];
        float dx = me.x - p.x, dy = me.y - p.y, dz = me.z - p.z;
        float r2 = fmaf(dx, dx, fmaf(dy, dy, dz * dz));
        float qj = p.w;
        float inv_r = fast_rsq(r2);
        e = fmaf(qj, inv_r, e);
        if (__any(r2 < 14.0625f)) {
          float r = r2 * inv_r;
          float arg = (r - 1.25f) * 0.4f;
          float argc = fminf(fmaxf(arg, 1e-6f), 1.f - 1e-6f);
          float tt = fast_rcp(argc) - fast_rcp(1.f - argc);
          float fs = fast_rcp(1.f + __expf(-tt));
          float delta = fs * (fast_rsq(r2 + 1.f) - inv_r);
          e = fmaf(qj, delta, e);
        }
      }
    }
  }
  if (a < 8 && w == (a & 3)) {              // distance 8: covered once (a < 8 side)
    int j0 = ((a + 8) & 15) * 64;
#pragma unroll 4
    for (int j = j0; j < j0 + 64; j++) {
      float4 p = posq[j];
      float dx = me.x - p.x, dy = me.y - p.y, dz = me.z - p.z;
      float r2 = fmaf(dx, dx, fmaf(dy, dy, dz * dz));
      float qj = p.w;
      float inv_r = fast_rsq(r2);
      e = fmaf(qj, inv_r, e);
      if (__any(r2 < 14.0625f)) {
        float r = r2 * inv_r;
        float arg = (r - 1.25f) * 0.4f;
        float argc = fminf(fmaxf(arg, 1e-6f), 1.f - 1e-6f);
        float tt = fast_rcp(argc) - fast_rcp(1.f - argc);
        float fs = fast_rcp(1.f + __expf(-tt));
        float delta = fs * (fast_rsq(r2 + 1.f) - inv_r);
        e = fmaf(qj, delta, e);
      }
    }
  }
  e *= me.w;
  float sred = wave_sum(e);
  if (l == 0) wred[w] = sred;
  __syncthreads();
  if (tid == 0)
    atomicAdd(&out[mol], 332.0636f * (wred[0] + wred[1] + wred[2] + wred[3]));
}

extern "C" void kernel_launch(void* const* d_in, const int* in_sizes, int n_in,
                              void* d_out, int out_size, void* d_ws, size_t ws_size,
                              hipStream_t stream) {
  const float* e_z     = (const float*)d_in[0];
  const float* charge  = (const float*)d_in[1];
  const float* xyz     = (const float*)d_in[2];
  const float* W_lin   = (const float*)d_in[3];
  const float* b_lin   = (const float*)d_in[4];
  const float* k_plus  = (const float*)d_in[5];
  const float* k_minus = (const float*)d_in[6];
  const float* v_plus  = (const float*)d_in[7];
  const float* v_minus = (const float*)d_in[8];
  const float* Wr1     = (const float*)d_in[9];
  const float* Wr2     = (const float*)d_in[10];
  const float* Wout    = (const float*)d_in[11];
  const float* w_e     = (const float*)d_in[12];
  const float* qz      = (const float*)d_in[13];
  const int*   z       = (const int*)d_in[14];
  float* out = (float*)d_out;
  float* ws  = (float*)d_ws;

  attn_sort_kernel<<<512, 256, 0, stream>>>(e_z, charge, xyz, W_lin, b_lin,
                                            k_plus, k_minus, Wr1, Wr2, Wout,
                                            w_e, ws, out);
  mlp_kernel<<<512, 256, 0, stream>>>(charge, v_plus, v_minus, z, qz, ws);
  pair_kernel<<<512, 256, 0, stream>>>(charge, ws, out);
}